// Round 1
// baseline (1496.596 us; speedup 1.0000x reference)
//
#include <hip/hip_runtime.h>
#include <hip/hip_bf16.h>

#define N_NODES 100000
#define N_EDGES 1600000
#define IN_DIM 64
#define HID 32
#define OUT_DIM 40

__device__ __forceinline__ void atomAdd(float* p, float v) {
    unsafeAtomicAdd(p, v);  // HW global_atomic_add_f32 (no CAS loop)
}

// Detect whether edge_index is stored as int64 (odd dwords all zero) or int32.
__global__ void detect_i64(const int* __restrict__ p, int* __restrict__ flagp) {
    __shared__ int s_any;
    if (threadIdx.x == 0) s_any = 0;
    __syncthreads();
    int any = 0;
    for (int i = threadIdx.x; i < 2048; i += blockDim.x) any |= p[2 * i + 1];
    if (any) atomicOr(&s_any, 1);
    __syncthreads();
    if (threadIdx.x == 0) *flagp = (s_any == 0) ? 1 : 0;  // 1 => int64 layout
}

// y_l = x @ Wl, y_r = x @ Wr   (x: [N, IN], W: [IN, HID] row-major)
template <int IN>
__global__ __launch_bounds__(256) void lin2_kernel(
    const float* __restrict__ x, const float* __restrict__ Wl,
    const float* __restrict__ Wr, float* __restrict__ yl,
    float* __restrict__ yr) {
    __shared__ float sWl[IN * HID];
    __shared__ float sWr[IN * HID];
    __shared__ float sX[8 * IN];
    for (int i = threadIdx.x; i < IN * HID; i += 256) {
        sWl[i] = Wl[i];
        sWr[i] = Wr[i];
    }
    const long long r0 = (long long)blockIdx.x * 8;
    for (int i = threadIdx.x; i < 8 * IN; i += 256) sX[i] = x[r0 * IN + i];
    __syncthreads();
    const int r = threadIdx.x >> 5;
    const int c = threadIdx.x & 31;
    float al = 0.f, ar = 0.f;
#pragma unroll
    for (int k = 0; k < IN; ++k) {
        const float xv = sX[r * IN + k];
        al += xv * sWl[k * HID + c];
        ar += xv * sWr[k * HID + c];
    }
    yl[(r0 + r) * HID + c] = al;
    yr[(r0 + r) * HID + c] = ar;
}

// agg[dst] += y[src]  (8 lanes per edge, float4 each); optionally count degree.
template <bool ADD_DEG>
__global__ __launch_bounds__(256) void scatter_kernel(
    const void* __restrict__ ei, const int* __restrict__ flagp,
    const float* __restrict__ y, float* __restrict__ agg,
    float* __restrict__ deg) {
    const long long idx = (long long)blockIdx.x * blockDim.x + threadIdx.x;
    if (idx >= (long long)N_EDGES * 8) return;
    const long long e = idx >> 3;
    const int q = (int)(idx & 7);
    int s, d;
    if (*flagp) {
        const long long* p = (const long long*)ei;
        s = (int)p[e];
        d = (int)p[N_EDGES + e];
    } else {
        const int* p = (const int*)ei;
        s = p[e];
        d = p[N_EDGES + e];
    }
    const float4 v = *(const float4*)(y + (long long)s * HID + q * 4);
    float* a = agg + (long long)d * HID + q * 4;
    atomAdd(a + 0, v.x);
    atomAdd(a + 1, v.y);
    atomAdd(a + 2, v.z);
    atomAdd(a + 3, v.w);
    if (ADD_DEG && q == 0) atomAdd(&deg[d], 1.0f);
}

__global__ void inv_kernel(float* __restrict__ deg) {
    const int i = blockIdx.x * blockDim.x + threadIdx.x;
    if (i < N_NODES) deg[i] = 1.0f / fmaxf(deg[i], 1.0f);
}

// h = relu(agg * inv_deg + b + yr), elementwise over [N, HID]
__global__ __launch_bounds__(256) void combine_kernel(
    const float* __restrict__ agg, const float* __restrict__ yr,
    const float* __restrict__ inv_deg, const float* __restrict__ b,
    float* __restrict__ h) {
    const long long idx = (long long)blockIdx.x * blockDim.x + threadIdx.x;
    if (idx >= (long long)N_NODES * 8) return;
    const long long row = idx >> 3;
    const int q = (int)(idx & 7);
    const float sc = inv_deg[row];
    const float4 a = *(const float4*)(agg + row * HID + q * 4);
    const float4 r = *(const float4*)(yr + row * HID + q * 4);
    const float4 bb = *(const float4*)(b + q * 4);
    float4 o;
    o.x = fmaxf(fmaf(a.x, sc, bb.x) + r.x, 0.f);
    o.y = fmaf(a.y, sc, bb.y) + r.y;
    o.y = fmaxf(o.y, 0.f);
    o.z = fmaxf(fmaf(a.z, sc, bb.z) + r.z, 0.f);
    o.w = fmaxf(fmaf(a.w, sc, bb.w) + r.w, 0.f);
    *(float4*)(h + row * HID + q * 4) = o;
}

// out = h @ w   (h: [N, HID], w: [HID, OUT])
__global__ __launch_bounds__(320) void out_kernel(const float* __restrict__ h,
                                                  const float* __restrict__ w,
                                                  float* __restrict__ out) {
    __shared__ float sW[HID * OUT_DIM];
    __shared__ float sH[8 * HID];
    for (int i = threadIdx.x; i < HID * OUT_DIM; i += 320) sW[i] = w[i];
    const long long r0 = (long long)blockIdx.x * 8;
    for (int i = threadIdx.x; i < 8 * HID; i += 320) sH[i] = h[r0 * HID + i];
    __syncthreads();
    const int r = threadIdx.x / OUT_DIM;
    const int c = threadIdx.x % OUT_DIM;
    float acc = 0.f;
#pragma unroll
    for (int k = 0; k < HID; ++k) acc += sH[r * HID + k] * sW[k * OUT_DIM + c];
    out[(r0 + r) * OUT_DIM + c] = acc;
}

extern "C" void kernel_launch(void* const* d_in, const int* in_sizes, int n_in,
                              void* d_out, int out_size, void* d_ws,
                              size_t ws_size, hipStream_t stream) {
    const float* x = (const float*)d_in[0];
    const void* ei = d_in[1];
    const float* W1l = (const float*)d_in[2];
    const float* b1 = (const float*)d_in[3];
    const float* W1r = (const float*)d_in[4];
    const float* W2l = (const float*)d_in[5];
    const float* b2 = (const float*)d_in[6];
    const float* W2r = (const float*)d_in[7];
    const float* w = (const float*)d_in[8];
    float* out = (float*)d_out;

    float* ws = (float*)d_ws;
    int* flagp = (int*)d_ws;
    float* deg = ws + 64;
    const long long NPAD = 100096;  // N rounded up to multiple of 64
    float* B1 = ws + 64 + NPAD;
    float* B2 = B1 + (long long)N_NODES * HID;
    float* B3 = B2 + (long long)N_NODES * HID;

    // zero flag + deg
    hipMemsetAsync(d_ws, 0, (size_t)(64 + NPAD) * sizeof(float), stream);
    detect_i64<<<1, 256, 0, stream>>>((const int*)ei, flagp);

    // layer 1: project first (32 cols), then scatter
    lin2_kernel<IN_DIM><<<N_NODES / 8, 256, 0, stream>>>(x, W1l, W1r, B1, B2);
    hipMemsetAsync(B3, 0, (size_t)N_NODES * HID * sizeof(float), stream);
    scatter_kernel<true><<<(N_EDGES * 8) / 256, 256, 0, stream>>>(ei, flagp, B1,
                                                                  B3, deg);
    inv_kernel<<<(N_NODES + 255) / 256, 256, 0, stream>>>(deg);
    combine_kernel<<<(N_NODES * 8) / 256, 256, 0, stream>>>(B3, B2, deg, b1,
                                                            B1);

    // layer 2
    lin2_kernel<HID><<<N_NODES / 8, 256, 0, stream>>>(B1, W2l, W2r, B2, B3);
    hipMemsetAsync(B1, 0, (size_t)N_NODES * HID * sizeof(float), stream);
    scatter_kernel<false><<<(N_EDGES * 8) / 256, 256, 0, stream>>>(ei, flagp,
                                                                   B2, B1, deg);
    combine_kernel<<<(N_NODES * 8) / 256, 256, 0, stream>>>(B1, B3, deg, b2,
                                                            B2);

    // output projection
    out_kernel<<<N_NODES / 8, 320, 0, stream>>>(B2, w, out);
}

// Round 2
// 349.180 us; speedup vs baseline: 4.2860x; 4.2860x over previous
//
#include <hip/hip_runtime.h>
#include <hip/hip_bf16.h>

#define N_NODES 100000
#define N_EDGES 1600000
#define IN_DIM 64
#define HID 32
#define OUT_DIM 40
#define SCAN_BLK 1024
#define N_SBLK ((N_NODES + SCAN_BLK - 1) / SCAN_BLK)  // 98

// Detect whether edge_index is stored as int64 (odd dwords all zero) or int32.
__global__ void detect_i64(const int* __restrict__ p, int* __restrict__ flagp) {
    __shared__ int s_any;
    if (threadIdx.x == 0) s_any = 0;
    __syncthreads();
    int any = 0;
    for (int i = threadIdx.x; i < 2048; i += blockDim.x) any |= p[2 * i + 1];
    if (any) atomicOr(&s_any, 1);
    __syncthreads();
    if (threadIdx.x == 0) *flagp = (s_any == 0) ? 1 : 0;  // 1 => int64 layout
}

__device__ __forceinline__ int load_idx(const void* ei, int i64, long long pos) {
    if (i64) return (int)((const long long*)ei)[pos];
    return ((const int*)ei)[pos];
}

// deg[dst]++
__global__ __launch_bounds__(512) void hist_kernel(const void* __restrict__ ei,
                                                   const int* __restrict__ flagp,
                                                   int* __restrict__ deg) {
    const long long e = (long long)blockIdx.x * blockDim.x + threadIdx.x;
    if (e >= N_EDGES) return;
    const int d = load_idx(ei, *flagp, N_EDGES + e);
    atomicAdd(&deg[d], 1);
}

// per-block exclusive scan of deg -> rowstart, block sums -> bsum
__global__ __launch_bounds__(SCAN_BLK) void scan1_kernel(
    const int* __restrict__ deg, int* __restrict__ rowstart,
    int* __restrict__ bsum) {
    __shared__ int s[SCAN_BLK];
    const int t = threadIdx.x;
    const int i = blockIdx.x * SCAN_BLK + t;
    const int v = (i < N_NODES) ? deg[i] : 0;
    s[t] = v;
    __syncthreads();
    for (int off = 1; off < SCAN_BLK; off <<= 1) {
        int add = (t >= off) ? s[t - off] : 0;
        __syncthreads();
        s[t] += add;
        __syncthreads();
    }
    if (i < N_NODES) rowstart[i] = s[t] - v;  // exclusive
    if (t == SCAN_BLK - 1) bsum[blockIdx.x] = s[t];
}

// exclusive scan of bsum (N_SBLK <= 128), single block of 128
__global__ __launch_bounds__(128) void scan2_kernel(int* __restrict__ bsum) {
    __shared__ int s[128];
    const int t = threadIdx.x;
    const int v = (t < N_SBLK) ? bsum[t] : 0;
    s[t] = v;
    __syncthreads();
    for (int off = 1; off < 128; off <<= 1) {
        int add = (t >= off) ? s[t - off] : 0;
        __syncthreads();
        s[t] += add;
        __syncthreads();
    }
    if (t < N_SBLK) bsum[t] = s[t] - v;
}

// rowstart += bsum[block]; cursor = rowstart; rowstart[N]=E
__global__ __launch_bounds__(512) void scan3_kernel(int* __restrict__ rowstart,
                                                    const int* __restrict__ bsum,
                                                    int* __restrict__ cursor) {
    const int i = blockIdx.x * blockDim.x + threadIdx.x;
    if (i < N_NODES) {
        const int r = rowstart[i] + bsum[i >> 10];
        rowstart[i] = r;
        cursor[i] = r;
    }
    if (i == N_NODES) rowstart[N_NODES] = N_EDGES;
}

// csr[slot] = src, slot = cursor[dst]++
__global__ __launch_bounds__(512) void place_kernel(const void* __restrict__ ei,
                                                    const int* __restrict__ flagp,
                                                    int* __restrict__ cursor,
                                                    int* __restrict__ csr) {
    const long long e = (long long)blockIdx.x * blockDim.x + threadIdx.x;
    if (e >= N_EDGES) return;
    const int i64 = *flagp;
    const int s = load_idx(ei, i64, e);
    const int d = load_idx(ei, i64, N_EDGES + e);
    const int slot = atomicAdd(&cursor[d], 1);
    csr[slot] = s;
}

// y_l = x @ Wl, y_r = x @ Wr   (x: [N, IN], W: [IN, HID] row-major)
template <int IN>
__global__ __launch_bounds__(256) void lin2_kernel(
    const float* __restrict__ x, const float* __restrict__ Wl,
    const float* __restrict__ Wr, float* __restrict__ yl,
    float* __restrict__ yr) {
    __shared__ float sWl[IN * HID];
    __shared__ float sWr[IN * HID];
    __shared__ float sX[8 * IN];
    for (int i = threadIdx.x; i < IN * HID; i += 256) {
        sWl[i] = Wl[i];
        sWr[i] = Wr[i];
    }
    const long long r0 = (long long)blockIdx.x * 8;
    for (int i = threadIdx.x; i < 8 * IN; i += 256) sX[i] = x[r0 * IN + i];
    __syncthreads();
    const int r = threadIdx.x >> 5;
    const int c = threadIdx.x & 31;
    float al = 0.f, ar = 0.f;
#pragma unroll
    for (int k = 0; k < IN; ++k) {
        const float xv = sX[r * IN + k];
        al += xv * sWl[k * HID + c];
        ar += xv * sWr[k * HID + c];
    }
    yl[(r0 + r) * HID + c] = al;
    yr[(r0 + r) * HID + c] = ar;
}

// per node: agg = sum_{e in CSR[node]} y[csr[e]]; h = relu(agg/deg + b + yr)
__global__ __launch_bounds__(256) void gather_combine(
    const int* __restrict__ rowstart, const int* __restrict__ csr,
    const float* __restrict__ y, const float* __restrict__ yr,
    const float* __restrict__ b, float* __restrict__ h) {
    const int node = blockIdx.x * 32 + (threadIdx.x >> 3);
    const int q = threadIdx.x & 7;
    if (node >= N_NODES) return;
    const int start = rowstart[node];
    const int end = rowstart[node + 1];
    float4 acc = make_float4(0.f, 0.f, 0.f, 0.f);
    int e = start;
    for (; e + 1 < end; e += 2) {
        const int s0 = csr[e];
        const int s1 = csr[e + 1];
        const float4 v0 = *(const float4*)(y + (long long)s0 * HID + q * 4);
        const float4 v1 = *(const float4*)(y + (long long)s1 * HID + q * 4);
        acc.x += v0.x + v1.x;
        acc.y += v0.y + v1.y;
        acc.z += v0.z + v1.z;
        acc.w += v0.w + v1.w;
    }
    if (e < end) {
        const int s0 = csr[e];
        const float4 v0 = *(const float4*)(y + (long long)s0 * HID + q * 4);
        acc.x += v0.x;
        acc.y += v0.y;
        acc.z += v0.z;
        acc.w += v0.w;
    }
    const float inv = 1.0f / fmaxf((float)(end - start), 1.0f);
    const float4 r = *(const float4*)(yr + (long long)node * HID + q * 4);
    const float4 bb = *(const float4*)(b + q * 4);
    float4 o;
    o.x = fmaxf(fmaf(acc.x, inv, bb.x) + r.x, 0.f);
    o.y = fmaxf(fmaf(acc.y, inv, bb.y) + r.y, 0.f);
    o.z = fmaxf(fmaf(acc.z, inv, bb.z) + r.z, 0.f);
    o.w = fmaxf(fmaf(acc.w, inv, bb.w) + r.w, 0.f);
    *(float4*)(h + (long long)node * HID + q * 4) = o;
}

// out = h @ w   (h: [N, HID], w: [HID, OUT])
__global__ __launch_bounds__(320) void out_kernel(const float* __restrict__ h,
                                                  const float* __restrict__ w,
                                                  float* __restrict__ out) {
    __shared__ float sW[HID * OUT_DIM];
    __shared__ float sH[8 * HID];
    for (int i = threadIdx.x; i < HID * OUT_DIM; i += 320) sW[i] = w[i];
    const long long r0 = (long long)blockIdx.x * 8;
    for (int i = threadIdx.x; i < 8 * HID; i += 320) sH[i] = h[r0 * HID + i];
    __syncthreads();
    const int r = threadIdx.x / OUT_DIM;
    const int c = threadIdx.x % OUT_DIM;
    float acc = 0.f;
#pragma unroll
    for (int k = 0; k < HID; ++k) acc += sH[r * HID + k] * sW[k * OUT_DIM + c];
    out[(r0 + r) * OUT_DIM + c] = acc;
}

extern "C" void kernel_launch(void* const* d_in, const int* in_sizes, int n_in,
                              void* d_out, int out_size, void* d_ws,
                              size_t ws_size, hipStream_t stream) {
    const float* x = (const float*)d_in[0];
    const void* ei = d_in[1];
    const float* W1l = (const float*)d_in[2];
    const float* b1 = (const float*)d_in[3];
    const float* W1r = (const float*)d_in[4];
    const float* W2l = (const float*)d_in[5];
    const float* b2 = (const float*)d_in[6];
    const float* W2r = (const float*)d_in[7];
    const float* w = (const float*)d_in[8];
    float* out = (float*)d_out;

    // workspace layout (4-byte units)
    int* ip = (int*)d_ws;
    int* flagp = ip;                       // [64]
    int* deg = ip + 64;                    // [100000]
    int* rowstart = deg + N_NODES;         // [100001] pad 100032
    int* cursor = rowstart + 100032;       // [100000]
    int* bsum = cursor + N_NODES;          // [128]
    int* csr = bsum + 128;                 // [1600000]
    float* B1 = (float*)(csr + N_EDGES);   // [N*HID]
    float* B2 = B1 + (long long)N_NODES * HID;
    float* B3 = B2 + (long long)N_NODES * HID;

    // zero deg histogram
    hipMemsetAsync(deg, 0, (size_t)N_NODES * sizeof(int), stream);
    detect_i64<<<1, 256, 0, stream>>>((const int*)ei, flagp);

    // ---- build CSR (counting sort by dst) ----
    hist_kernel<<<(N_EDGES + 511) / 512, 512, 0, stream>>>(ei, flagp, deg);
    scan1_kernel<<<N_SBLK, SCAN_BLK, 0, stream>>>(deg, rowstart, bsum);
    scan2_kernel<<<1, 128, 0, stream>>>(bsum);
    scan3_kernel<<<(N_NODES + 512) / 512, 512, 0, stream>>>(rowstart, bsum,
                                                            cursor);
    place_kernel<<<(N_EDGES + 511) / 512, 512, 0, stream>>>(ei, flagp, cursor,
                                                            csr);

    // ---- layer 1: project first (HID cols), then gather-mean (fused) ----
    lin2_kernel<IN_DIM><<<N_NODES / 8, 256, 0, stream>>>(x, W1l, W1r, B1, B2);
    gather_combine<<<(N_NODES + 31) / 32, 256, 0, stream>>>(rowstart, csr, B1,
                                                            B2, b1, B3);

    // ---- layer 2 ----
    lin2_kernel<HID><<<N_NODES / 8, 256, 0, stream>>>(B3, W2l, W2r, B1, B2);
    gather_combine<<<(N_NODES + 31) / 32, 256, 0, stream>>>(rowstart, csr, B1,
                                                            B2, b2, B3);

    // ---- output projection ----
    out_kernel<<<N_NODES / 8, 320, 0, stream>>>(B3, w, out);
}

// Round 3
// 196.908 us; speedup vs baseline: 7.6005x; 1.7733x over previous
//
#include <hip/hip_runtime.h>
#include <hip/hip_bf16.h>

#define N_NODES 100000
#define N_EDGES 1600000
#define IN_DIM 64
#define HID 32
#define OUT_DIM 40

#define NBUK 98      // buckets: dst >> 10
#define BCAP 18000   // per-bucket capacity (avg 16384, sigma ~127)
#define BIN_TILE 8192

// Detect whether edge_index is stored as int64 (odd dwords all zero) or int32.
__global__ void detect_i64(const int* __restrict__ p, int* __restrict__ flagp) {
    __shared__ int s_any;
    if (threadIdx.x == 0) s_any = 0;
    __syncthreads();
    int any = 0;
    for (int i = threadIdx.x; i < 2048; i += blockDim.x) any |= p[2 * i + 1];
    if (any) atomicOr(&s_any, 1);
    __syncthreads();
    if (threadIdx.x == 0) *flagp = (s_any == 0) ? 1 : 0;  // 1 => int64 layout
}

__device__ __forceinline__ int load_idx(const void* ei, int i64, long long pos) {
    if (i64) return (int)((const long long*)ei)[pos];
    return ((const int*)ei)[pos];
}

// Pass 1: bin edges by dst>>10 into per-bucket regions, coalesced writes.
// Packed value: (src << 10) | (dst & 1023)  -- 27 bits.
__global__ __launch_bounds__(1024) void bin_kernel(const void* __restrict__ ei,
                                                   const int* __restrict__ flagp,
                                                   int* __restrict__ cnt,
                                                   int* __restrict__ binned) {
    __shared__ int lcount[NBUK];
    __shared__ int lscan[NBUK + 1];
    __shared__ int lcur[NBUK];
    __shared__ int lbase[NBUK];
    __shared__ int stage[BIN_TILE];
    const int t = threadIdx.x;
    for (int i = t; i < NBUK; i += 1024) lcount[i] = 0;
    __syncthreads();

    const long long e0 = (long long)blockIdx.x * BIN_TILE;
    const int i64 = *flagp;
    int vv[8], bb[8];
#pragma unroll
    for (int k = 0; k < 8; ++k) {
        const long long e = e0 + (long long)k * 1024 + t;
        if (e < N_EDGES) {
            const int s = load_idx(ei, i64, e);
            const int d = load_idx(ei, i64, N_EDGES + e);
            bb[k] = d >> 10;
            vv[k] = (s << 10) | (d & 1023);
            atomicAdd(&lcount[bb[k]], 1);
        } else {
            bb[k] = -1;
        }
    }
    __syncthreads();
    if (t == 0) {
        int acc = 0;
        for (int i = 0; i < NBUK; ++i) {
            lscan[i] = acc;
            acc += lcount[i];
        }
        lscan[NBUK] = acc;
    }
    __syncthreads();
    // reserve global runs, init local cursors
    for (int i = t; i < NBUK; i += 1024) {
        const int c = lcount[i];
        lbase[i] = i * BCAP + (c > 0 ? atomicAdd(&cnt[i], c) : 0);
        lcur[i] = lscan[i];
    }
    __syncthreads();
    // place into LDS stage grouped by bucket
#pragma unroll
    for (int k = 0; k < 8; ++k) {
        if (bb[k] >= 0) {
            const int pos = atomicAdd(&lcur[bb[k]], 1);
            stage[pos] = vv[k];
        }
    }
    __syncthreads();
    // coalesced copy-out (binary search bucket of each stage slot)
    const int total = lscan[NBUK];
    for (int j = t; j < total; j += 1024) {
        int lo = 0, hi = NBUK;
        while (hi - lo > 1) {
            const int mid = (lo + hi) >> 1;
            if (lscan[mid] <= j) lo = mid;
            else hi = mid;
        }
        binned[lbase[lo] + (j - lscan[lo])] = stage[j];
    }
}

// small scan over bucket counts -> per-bucket CSR base; rowstart[N] = E
__global__ __launch_bounds__(128) void bscan_kernel(const int* __restrict__ cnt,
                                                    int* __restrict__ bbase,
                                                    int* __restrict__ rowstart) {
    __shared__ int s[128];
    const int t = threadIdx.x;
    const int v = (t < NBUK) ? cnt[t] : 0;
    s[t] = v;
    __syncthreads();
    for (int off = 1; off < 128; off <<= 1) {
        const int add = (t >= off) ? s[t - off] : 0;
        __syncthreads();
        s[t] += add;
        __syncthreads();
    }
    if (t < NBUK) bbase[t] = s[t] - v;
    if (t == 0) rowstart[N_NODES] = N_EDGES;
}

// Pass 2: per-bucket LDS counting sort -> rowstart + csr (src per slot).
__global__ __launch_bounds__(1024) void sort_kernel(const int* __restrict__ cnt,
                                                    const int* __restrict__ bbase,
                                                    const int* __restrict__ binned,
                                                    int* __restrict__ rowstart,
                                                    int* __restrict__ csr) {
    __shared__ int counts[1024];
    __shared__ int sc[1024];
    const int b = blockIdx.x;
    const int t = threadIdx.x;
    const int n = cnt[b];
    const int base = bbase[b];
    const int* __restrict__ bin = binned + (long long)b * BCAP;
    counts[t] = 0;
    __syncthreads();
    for (int i = t; i < n; i += 1024) atomicAdd(&counts[bin[i] & 1023], 1);
    __syncthreads();
    const int v = counts[t];
    sc[t] = v;
    __syncthreads();
    for (int off = 1; off < 1024; off <<= 1) {
        const int add = (t >= off) ? sc[t - off] : 0;
        __syncthreads();
        sc[t] += add;
        __syncthreads();
    }
    const int excl = sc[t] - v;
    const int node = b * 1024 + t;
    if (node < N_NODES) rowstart[node] = base + excl;
    counts[t] = excl;  // reuse as local cursor
    __syncthreads();
    for (int i = t; i < n; i += 1024) {
        const int vv = bin[i];
        const int pos = atomicAdd(&counts[vv & 1023], 1);
        csr[base + pos] = vv >> 10;
    }
}

// y_l = x @ Wl, y_r = x @ Wr   (x: [N, IN], W: [IN, HID] row-major)
template <int IN>
__global__ __launch_bounds__(256) void lin2_kernel(
    const float* __restrict__ x, const float* __restrict__ Wl,
    const float* __restrict__ Wr, float* __restrict__ yl,
    float* __restrict__ yr) {
    __shared__ float sWl[IN * HID];
    __shared__ float sWr[IN * HID];
    __shared__ float sX[8 * IN];
    for (int i = threadIdx.x; i < IN * HID; i += 256) {
        sWl[i] = Wl[i];
        sWr[i] = Wr[i];
    }
    const long long r0 = (long long)blockIdx.x * 8;
    for (int i = threadIdx.x; i < 8 * IN; i += 256) sX[i] = x[r0 * IN + i];
    __syncthreads();
    const int r = threadIdx.x >> 5;
    const int c = threadIdx.x & 31;
    float al = 0.f, ar = 0.f;
#pragma unroll
    for (int k = 0; k < IN; ++k) {
        const float xv = sX[r * IN + k];
        al += xv * sWl[k * HID + c];
        ar += xv * sWr[k * HID + c];
    }
    yl[(r0 + r) * HID + c] = al;
    yr[(r0 + r) * HID + c] = ar;
}

// per node: agg = sum_{e in CSR[node]} y[csr[e]]; h = relu(agg/deg + b + yr)
__global__ __launch_bounds__(256) void gather_combine(
    const int* __restrict__ rowstart, const int* __restrict__ csr,
    const float* __restrict__ y, const float* __restrict__ yr,
    const float* __restrict__ b, float* __restrict__ h) {
    const int node = blockIdx.x * 32 + (threadIdx.x >> 3);
    const int q = threadIdx.x & 7;
    if (node >= N_NODES) return;
    const int start = rowstart[node];
    const int end = rowstart[node + 1];
    float4 acc = make_float4(0.f, 0.f, 0.f, 0.f);
    int e = start;
    for (; e + 1 < end; e += 2) {
        const int s0 = csr[e];
        const int s1 = csr[e + 1];
        const float4 v0 = *(const float4*)(y + (long long)s0 * HID + q * 4);
        const float4 v1 = *(const float4*)(y + (long long)s1 * HID + q * 4);
        acc.x += v0.x + v1.x;
        acc.y += v0.y + v1.y;
        acc.z += v0.z + v1.z;
        acc.w += v0.w + v1.w;
    }
    if (e < end) {
        const int s0 = csr[e];
        const float4 v0 = *(const float4*)(y + (long long)s0 * HID + q * 4);
        acc.x += v0.x;
        acc.y += v0.y;
        acc.z += v0.z;
        acc.w += v0.w;
    }
    const float inv = 1.0f / fmaxf((float)(end - start), 1.0f);
    const float4 r = *(const float4*)(yr + (long long)node * HID + q * 4);
    const float4 bb = *(const float4*)(b + q * 4);
    float4 o;
    o.x = fmaxf(fmaf(acc.x, inv, bb.x) + r.x, 0.f);
    o.y = fmaxf(fmaf(acc.y, inv, bb.y) + r.y, 0.f);
    o.z = fmaxf(fmaf(acc.z, inv, bb.z) + r.z, 0.f);
    o.w = fmaxf(fmaf(acc.w, inv, bb.w) + r.w, 0.f);
    *(float4*)(h + (long long)node * HID + q * 4) = o;
}

// out = h @ w   (h: [N, HID], w: [HID, OUT])
__global__ __launch_bounds__(320) void out_kernel(const float* __restrict__ h,
                                                  const float* __restrict__ w,
                                                  float* __restrict__ out) {
    __shared__ float sW[HID * OUT_DIM];
    __shared__ float sH[8 * HID];
    for (int i = threadIdx.x; i < HID * OUT_DIM; i += 320) sW[i] = w[i];
    const long long r0 = (long long)blockIdx.x * 8;
    for (int i = threadIdx.x; i < 8 * HID; i += 320) sH[i] = h[r0 * HID + i];
    __syncthreads();
    const int r = threadIdx.x / OUT_DIM;
    const int c = threadIdx.x % OUT_DIM;
    float acc = 0.f;
#pragma unroll
    for (int k = 0; k < HID; ++k) acc += sH[r * HID + k] * sW[k * OUT_DIM + c];
    out[(r0 + r) * OUT_DIM + c] = acc;
}

extern "C" void kernel_launch(void* const* d_in, const int* in_sizes, int n_in,
                              void* d_out, int out_size, void* d_ws,
                              size_t ws_size, hipStream_t stream) {
    const float* x = (const float*)d_in[0];
    const void* ei = d_in[1];
    const float* W1l = (const float*)d_in[2];
    const float* b1 = (const float*)d_in[3];
    const float* W1r = (const float*)d_in[4];
    const float* W2l = (const float*)d_in[5];
    const float* b2 = (const float*)d_in[6];
    const float* W2r = (const float*)d_in[7];
    const float* w = (const float*)d_in[8];
    float* out = (float*)d_out;

    // workspace layout (4-byte units)
    int* ip = (int*)d_ws;
    int* flagp = ip;                        // [64]
    int* cnt = ip + 64;                     // [98] pad to 128
    int* bbase = ip + 192;                  // [98] pad to 128
    int* rowstart = ip + 320;               // [100001] pad 100032
    int* csr = rowstart + 100032;           // [1600000]
    float* B1 = (float*)(csr + N_EDGES);    // [N*HID]
    float* B2 = B1 + (long long)N_NODES * HID;
    float* B3 = B2 + (long long)N_NODES * HID;
    // binned aliases B1: lifetime ends before lin2 writes B1 (same stream)
    int* binned = (int*)B1;                 // [NBUK*BCAP] = 1.764M ints < 3.2M

    hipMemsetAsync(cnt, 0, 128 * sizeof(int), stream);
    detect_i64<<<1, 256, 0, stream>>>((const int*)ei, flagp);

    // ---- build CSR: bucket pass + per-bucket LDS counting sort ----
    bin_kernel<<<(N_EDGES + BIN_TILE - 1) / BIN_TILE, 1024, 0, stream>>>(
        ei, flagp, cnt, binned);
    bscan_kernel<<<1, 128, 0, stream>>>(cnt, bbase, rowstart);
    sort_kernel<<<NBUK, 1024, 0, stream>>>(cnt, bbase, binned, rowstart, csr);

    // ---- layer 1: project first (HID cols), then gather-mean (fused) ----
    lin2_kernel<IN_DIM><<<N_NODES / 8, 256, 0, stream>>>(x, W1l, W1r, B2, B3);
    gather_combine<<<(N_NODES + 31) / 32, 256, 0, stream>>>(rowstart, csr, B2,
                                                            B3, b1, B1);

    // ---- layer 2 ----
    lin2_kernel<HID><<<N_NODES / 8, 256, 0, stream>>>(B1, W2l, W2r, B2, B3);
    gather_combine<<<(N_NODES + 31) / 32, 256, 0, stream>>>(rowstart, csr, B2,
                                                            B3, b2, B1);

    // ---- output projection ----
    out_kernel<<<N_NODES / 8, 320, 0, stream>>>(B1, w, out);
}

// Round 4
// 151.962 us; speedup vs baseline: 9.8485x; 1.2958x over previous
//
#include <hip/hip_runtime.h>
#include <hip/hip_bf16.h>

#define N_NODES 100000
#define N_EDGES 1600000
#define IN_DIM 64
#define HID 32
#define OUT_DIM 40

#define NBUK 98      // buckets: dst >> 10
#define BCAP 18000   // per-bucket capacity (avg 16327, sigma ~127)
#define BIN_TILE 8192

__device__ __forceinline__ float bf2f(unsigned short u) {
    return __uint_as_float(((unsigned int)u) << 16);
}
__device__ __forceinline__ unsigned short f2bf(float f) {
    unsigned int u = __float_as_uint(f);
    u = (u + 0x7fffu + ((u >> 16) & 1u)) >> 16;  // RNE
    return (unsigned short)u;
}

// Detect whether edge_index is stored as int64 (odd dwords all zero) or int32.
__global__ void detect_i64(const int* __restrict__ p, int* __restrict__ flagp) {
    __shared__ int s_any;
    if (threadIdx.x == 0) s_any = 0;
    __syncthreads();
    int any = 0;
    for (int i = threadIdx.x; i < 2048; i += blockDim.x) any |= p[2 * i + 1];
    if (any) atomicOr(&s_any, 1);
    __syncthreads();
    if (threadIdx.x == 0) *flagp = (s_any == 0) ? 1 : 0;  // 1 => int64 layout
}

__device__ __forceinline__ int load_idx(const void* ei, int i64, long long pos) {
    if (i64) return (int)((const long long*)ei)[pos];
    return ((const int*)ei)[pos];
}

// Pass 1: bin edges by dst>>10 into per-bucket regions, coalesced writes.
// Packed value: (src << 10) | (dst & 1023)  -- 27 bits.
__global__ __launch_bounds__(1024) void bin_kernel(const void* __restrict__ ei,
                                                   const int* __restrict__ flagp,
                                                   int* __restrict__ cnt,
                                                   int* __restrict__ binned) {
    __shared__ int lcount[NBUK];
    __shared__ int lscan[NBUK + 1];
    __shared__ int lcur[NBUK];
    __shared__ int lbase[NBUK];
    __shared__ int stage[BIN_TILE];
    const int t = threadIdx.x;
    for (int i = t; i < NBUK; i += 1024) lcount[i] = 0;
    __syncthreads();

    const long long e0 = (long long)blockIdx.x * BIN_TILE;
    const int i64 = *flagp;
    int vv[8], bb[8];
#pragma unroll
    for (int k = 0; k < 8; ++k) {
        const long long e = e0 + (long long)k * 1024 + t;
        if (e < N_EDGES) {
            const int s = load_idx(ei, i64, e);
            const int d = load_idx(ei, i64, N_EDGES + e);
            bb[k] = d >> 10;
            vv[k] = (s << 10) | (d & 1023);
            atomicAdd(&lcount[bb[k]], 1);
        } else {
            bb[k] = -1;
        }
    }
    __syncthreads();
    if (t == 0) {
        int acc = 0;
        for (int i = 0; i < NBUK; ++i) {
            lscan[i] = acc;
            acc += lcount[i];
        }
        lscan[NBUK] = acc;
    }
    __syncthreads();
    for (int i = t; i < NBUK; i += 1024) {
        const int c = lcount[i];
        lbase[i] = i * BCAP + (c > 0 ? atomicAdd(&cnt[i], c) : 0);
        lcur[i] = lscan[i];
    }
    __syncthreads();
#pragma unroll
    for (int k = 0; k < 8; ++k) {
        if (bb[k] >= 0) {
            const int pos = atomicAdd(&lcur[bb[k]], 1);
            stage[pos] = vv[k];
        }
    }
    __syncthreads();
    const int total = lscan[NBUK];
    for (int j = t; j < total; j += 1024) {
        int lo = 0, hi = NBUK;
        while (hi - lo > 1) {
            const int mid = (lo + hi) >> 1;
            if (lscan[mid] <= j) lo = mid;
            else hi = mid;
        }
        binned[lbase[lo] + (j - lscan[lo])] = stage[j];
    }
}

// small scan over bucket counts -> per-bucket CSR base; rowstart[N] = E
__global__ __launch_bounds__(128) void bscan_kernel(const int* __restrict__ cnt,
                                                    int* __restrict__ bbase,
                                                    int* __restrict__ rowstart) {
    __shared__ int s[128];
    const int t = threadIdx.x;
    const int v = (t < NBUK) ? cnt[t] : 0;
    s[t] = v;
    __syncthreads();
    for (int off = 1; off < 128; off <<= 1) {
        const int add = (t >= off) ? s[t - off] : 0;
        __syncthreads();
        s[t] += add;
        __syncthreads();
    }
    if (t < NBUK) bbase[t] = s[t] - v;
    if (t == 0) rowstart[N_NODES] = N_EDGES;
}

// Pass 2: per-bucket LDS counting sort -> rowstart + csr (src per slot).
__global__ __launch_bounds__(1024) void sort_kernel(const int* __restrict__ cnt,
                                                    const int* __restrict__ bbase,
                                                    const int* __restrict__ binned,
                                                    int* __restrict__ rowstart,
                                                    int* __restrict__ csr) {
    __shared__ int counts[1024];
    __shared__ int sc[1024];
    const int b = blockIdx.x;
    const int t = threadIdx.x;
    const int n = cnt[b];
    const int base = bbase[b];
    const int* __restrict__ bin = binned + (long long)b * BCAP;
    counts[t] = 0;
    __syncthreads();
    for (int i = t; i < n; i += 1024) atomicAdd(&counts[bin[i] & 1023], 1);
    __syncthreads();
    const int v = counts[t];
    sc[t] = v;
    __syncthreads();
    for (int off = 1; off < 1024; off <<= 1) {
        const int add = (t >= off) ? sc[t - off] : 0;
        __syncthreads();
        sc[t] += add;
        __syncthreads();
    }
    const int excl = sc[t] - v;
    const int node = b * 1024 + t;
    if (node < N_NODES) rowstart[node] = base + excl;
    counts[t] = excl;  // reuse as local cursor
    __syncthreads();
    for (int i = t; i < n; i += 1024) {
        const int vv = bin[i];
        const int pos = atomicAdd(&counts[vv & 1023], 1);
        csr[base + pos] = vv >> 10;
    }
}

// Layer-1 projection: yl(bf16) = x @ Wl, yr(fp32) = x @ Wr
// 64 rows/block, 256 threads: thread = (row-group rg = t>>5 -> 8 rows, col c = t&31)
__global__ __launch_bounds__(256) void lin1_kernel(
    const float* __restrict__ x, const float* __restrict__ Wl,
    const float* __restrict__ Wr, unsigned short* __restrict__ yl,
    float* __restrict__ yr) {
    __shared__ float sWl[IN_DIM * HID];  // [k][c] 8 KB
    __shared__ float sWr[IN_DIM * HID];  // 8 KB
    __shared__ float sX[64 * IN_DIM];    // [r][k] 16 KB
    const int t = threadIdx.x;
    for (int i = t; i < IN_DIM * HID; i += 256) {
        sWl[i] = Wl[i];
        sWr[i] = Wr[i];
    }
    const long long r0 = (long long)blockIdx.x * 64;
    const int nrows = (int)((N_NODES - r0) < 64 ? (N_NODES - r0) : 64);
    const float4* xv = (const float4*)(x + r0 * IN_DIM);
    float4* sXv = (float4*)sX;
    for (int i = t; i < nrows * 16; i += 256) sXv[i] = xv[i];
    __syncthreads();

    const int c = t & 31;
    const int rbase = (t >> 5) * 8;
    float al[8] = {0, 0, 0, 0, 0, 0, 0, 0};
    float ar[8] = {0, 0, 0, 0, 0, 0, 0, 0};
    for (int k = 0; k < IN_DIM; k += 4) {
        const float wl0 = sWl[(k + 0) * HID + c];
        const float wl1 = sWl[(k + 1) * HID + c];
        const float wl2 = sWl[(k + 2) * HID + c];
        const float wl3 = sWl[(k + 3) * HID + c];
        const float wr0 = sWr[(k + 0) * HID + c];
        const float wr1 = sWr[(k + 1) * HID + c];
        const float wr2 = sWr[(k + 2) * HID + c];
        const float wr3 = sWr[(k + 3) * HID + c];
#pragma unroll
        for (int r = 0; r < 8; ++r) {
            const float4 xv4 = *(const float4*)&sX[(rbase + r) * IN_DIM + k];
            al[r] = fmaf(xv4.x, wl0, al[r]);
            al[r] = fmaf(xv4.y, wl1, al[r]);
            al[r] = fmaf(xv4.z, wl2, al[r]);
            al[r] = fmaf(xv4.w, wl3, al[r]);
            ar[r] = fmaf(xv4.x, wr0, ar[r]);
            ar[r] = fmaf(xv4.y, wr1, ar[r]);
            ar[r] = fmaf(xv4.z, wr2, ar[r]);
            ar[r] = fmaf(xv4.w, wr3, ar[r]);
        }
    }
    // fp32 yr: direct coalesced scalar stores
#pragma unroll
    for (int r = 0; r < 8; ++r) {
        if (rbase + r < nrows) yr[(r0 + rbase + r) * HID + c] = ar[r];
    }
    // bf16 yl: restage through LDS (sX dead) for vectorized store
    __syncthreads();
    unsigned short* sB = (unsigned short*)sX;
#pragma unroll
    for (int r = 0; r < 8; ++r) {
        if (rbase + r < nrows) sB[(rbase + r) * HID + c] = f2bf(al[r]);
    }
    __syncthreads();
    uint4* dst = (uint4*)(yl + r0 * HID);
    const uint4* src = (const uint4*)sB;
    for (int i = t; i < nrows * 4; i += 256) dst[i] = src[i];
}

// Fused: gather-mean(Y1l bf16) + combine(Y1r,b1) -> h1 (LDS) -> y2l/y2r = h1 @ W2l/W2r
__global__ __launch_bounds__(256) void gather_lin2(
    const int* __restrict__ rowstart, const int* __restrict__ csr,
    const unsigned short* __restrict__ yl, const float* __restrict__ yr,
    const float* __restrict__ b, const float* __restrict__ W2l,
    const float* __restrict__ W2r, unsigned short* __restrict__ y2l,
    float* __restrict__ y2r) {
    __shared__ float sH[32 * 33];
    __shared__ float sW2l[HID * HID];
    __shared__ float sW2r[HID * HID];
    const int t = threadIdx.x;
    for (int i = t; i < HID * HID; i += 256) {
        sW2l[i] = W2l[i];
        sW2r[i] = W2r[i];
    }
    const int ln = t >> 3;
    const int q = t & 7;
    const int node = blockIdx.x * 32 + ln;
    const int start = rowstart[node];
    const int end = rowstart[node + 1];
    float ax = 0.f, ay = 0.f, az = 0.f, aw = 0.f;
    int e = start;
    for (; e + 1 < end; e += 2) {
        const int s0 = csr[e];
        const int s1 = csr[e + 1];
        const ushort4 v0 = *(const ushort4*)(yl + (long long)s0 * HID + q * 4);
        const ushort4 v1 = *(const ushort4*)(yl + (long long)s1 * HID + q * 4);
        ax += bf2f(v0.x) + bf2f(v1.x);
        ay += bf2f(v0.y) + bf2f(v1.y);
        az += bf2f(v0.z) + bf2f(v1.z);
        aw += bf2f(v0.w) + bf2f(v1.w);
    }
    if (e < end) {
        const int s0 = csr[e];
        const ushort4 v0 = *(const ushort4*)(yl + (long long)s0 * HID + q * 4);
        ax += bf2f(v0.x);
        ay += bf2f(v0.y);
        az += bf2f(v0.z);
        aw += bf2f(v0.w);
    }
    const float inv = 1.0f / fmaxf((float)(end - start), 1.0f);
    const float4 rr = *(const float4*)(yr + (long long)node * HID + q * 4);
    const float4 bb = *(const float4*)(b + q * 4);
    sH[ln * 33 + q * 4 + 0] = fmaxf(fmaf(ax, inv, bb.x) + rr.x, 0.f);
    sH[ln * 33 + q * 4 + 1] = fmaxf(fmaf(ay, inv, bb.y) + rr.y, 0.f);
    sH[ln * 33 + q * 4 + 2] = fmaxf(fmaf(az, inv, bb.z) + rr.z, 0.f);
    sH[ln * 33 + q * 4 + 3] = fmaxf(fmaf(aw, inv, bb.w) + rr.w, 0.f);
    __syncthreads();
    float l0 = 0, l1 = 0, l2 = 0, l3 = 0, m0 = 0, m1 = 0, m2 = 0, m3 = 0;
#pragma unroll
    for (int k = 0; k < HID; ++k) {
        const float hk = sH[ln * 33 + k];
        const float4 wl = *(const float4*)&sW2l[k * HID + q * 4];
        const float4 wr = *(const float4*)&sW2r[k * HID + q * 4];
        l0 = fmaf(hk, wl.x, l0);
        l1 = fmaf(hk, wl.y, l1);
        l2 = fmaf(hk, wl.z, l2);
        l3 = fmaf(hk, wl.w, l3);
        m0 = fmaf(hk, wr.x, m0);
        m1 = fmaf(hk, wr.y, m1);
        m2 = fmaf(hk, wr.z, m2);
        m3 = fmaf(hk, wr.w, m3);
    }
    *(float4*)(y2r + (long long)node * HID + q * 4) = make_float4(m0, m1, m2, m3);
    ushort4 p;
    p.x = f2bf(l0);
    p.y = f2bf(l1);
    p.z = f2bf(l2);
    p.w = f2bf(l3);
    *(ushort4*)(y2l + (long long)node * HID + q * 4) = p;
}

// Fused: gather-mean(Y2l bf16) + combine(Y2r,b2) -> h2 (LDS) -> out = h2 @ w
__global__ __launch_bounds__(256) void gather_out(
    const int* __restrict__ rowstart, const int* __restrict__ csr,
    const unsigned short* __restrict__ yl, const float* __restrict__ yr,
    const float* __restrict__ b, const float* __restrict__ w,
    float* __restrict__ out) {
    __shared__ float sH[32 * 33];
    __shared__ float sW[HID * OUT_DIM];  // 5 KB
    const int t = threadIdx.x;
    for (int i = t; i < HID * OUT_DIM; i += 256) sW[i] = w[i];
    const int ln = t >> 3;
    const int q = t & 7;
    const int node = blockIdx.x * 32 + ln;
    const int start = rowstart[node];
    const int end = rowstart[node + 1];
    float ax = 0.f, ay = 0.f, az = 0.f, aw = 0.f;
    int e = start;
    for (; e + 1 < end; e += 2) {
        const int s0 = csr[e];
        const int s1 = csr[e + 1];
        const ushort4 v0 = *(const ushort4*)(yl + (long long)s0 * HID + q * 4);
        const ushort4 v1 = *(const ushort4*)(yl + (long long)s1 * HID + q * 4);
        ax += bf2f(v0.x) + bf2f(v1.x);
        ay += bf2f(v0.y) + bf2f(v1.y);
        az += bf2f(v0.z) + bf2f(v1.z);
        aw += bf2f(v0.w) + bf2f(v1.w);
    }
    if (e < end) {
        const int s0 = csr[e];
        const ushort4 v0 = *(const ushort4*)(yl + (long long)s0 * HID + q * 4);
        ax += bf2f(v0.x);
        ay += bf2f(v0.y);
        az += bf2f(v0.z);
        aw += bf2f(v0.w);
    }
    const float inv = 1.0f / fmaxf((float)(end - start), 1.0f);
    const float4 rr = *(const float4*)(yr + (long long)node * HID + q * 4);
    const float4 bb = *(const float4*)(b + q * 4);
    sH[ln * 33 + q * 4 + 0] = fmaxf(fmaf(ax, inv, bb.x) + rr.x, 0.f);
    sH[ln * 33 + q * 4 + 1] = fmaxf(fmaf(ay, inv, bb.y) + rr.y, 0.f);
    sH[ln * 33 + q * 4 + 2] = fmaxf(fmaf(az, inv, bb.z) + rr.z, 0.f);
    sH[ln * 33 + q * 4 + 3] = fmaxf(fmaf(aw, inv, bb.w) + rr.w, 0.f);
    __syncthreads();
    float acc[5] = {0, 0, 0, 0, 0};
#pragma unroll
    for (int k = 0; k < HID; ++k) {
        const float hk = sH[ln * 33 + k];
#pragma unroll
        for (int j = 0; j < 5; ++j)
            acc[j] = fmaf(hk, sW[k * OUT_DIM + q + 8 * j], acc[j]);
    }
#pragma unroll
    for (int j = 0; j < 5; ++j) out[(long long)node * OUT_DIM + q + 8 * j] = acc[j];
}

extern "C" void kernel_launch(void* const* d_in, const int* in_sizes, int n_in,
                              void* d_out, int out_size, void* d_ws,
                              size_t ws_size, hipStream_t stream) {
    const float* x = (const float*)d_in[0];
    const void* ei = d_in[1];
    const float* W1l = (const float*)d_in[2];
    const float* b1 = (const float*)d_in[3];
    const float* W1r = (const float*)d_in[4];
    const float* W2l = (const float*)d_in[5];
    const float* b2 = (const float*)d_in[6];
    const float* W2r = (const float*)d_in[7];
    const float* w = (const float*)d_in[8];
    float* out = (float*)d_out;

    // workspace layout (4-byte units)
    int* ip = (int*)d_ws;
    int* flagp = ip;                        // [64]
    int* cnt = ip + 64;                     // [98] pad to 128
    int* bbase = ip + 192;                  // [98] pad to 128
    int* rowstart = ip + 320;               // [100001] pad 100032
    int* csr = rowstart + 100032;           // [1600000]
    float* Y1r = (float*)(csr + N_EDGES);   // [N*HID] fp32
    float* Y2r = Y1r + (long long)N_NODES * HID;            // [N*HID] fp32
    unsigned short* Y1l = (unsigned short*)(Y2r + (long long)N_NODES * HID);
    unsigned short* Y2l = Y1l + (long long)N_NODES * HID;
    // binned aliases Y2r: dead after sort_kernel, before gather_lin2 writes Y2r
    int* binned = (int*)Y2r;                // [NBUK*BCAP] = 1.764M ints < 3.2M

    hipMemsetAsync(cnt, 0, 128 * sizeof(int), stream);
    detect_i64<<<1, 256, 0, stream>>>((const int*)ei, flagp);

    // ---- build CSR: bucket pass + per-bucket LDS counting sort ----
    bin_kernel<<<(N_EDGES + BIN_TILE - 1) / BIN_TILE, 1024, 0, stream>>>(
        ei, flagp, cnt, binned);
    bscan_kernel<<<1, 128, 0, stream>>>(cnt, bbase, rowstart);
    sort_kernel<<<NBUK, 1024, 0, stream>>>(cnt, bbase, binned, rowstart, csr);

    // ---- layer 1 projection ----
    lin1_kernel<<<(N_NODES + 63) / 64, 256, 0, stream>>>(x, W1l, W1r, Y1l, Y1r);

    // ---- fused gather1 + combine + layer-2 projection ----
    gather_lin2<<<N_NODES / 32, 256, 0, stream>>>(rowstart, csr, Y1l, Y1r, b1,
                                                  W2l, W2r, Y2l, Y2r);

    // ---- fused gather2 + combine + output projection ----
    gather_out<<<N_NODES / 32, 256, 0, stream>>>(rowstart, csr, Y2l, Y2r, b2, w,
                                                 out);
}